// Round 9
// baseline (41.301 us; speedup 1.0000x reference)
//
#include <hip/hip_runtime.h>
#include <hip/hip_bf16.h>

// Chamfer distance via MFMA (bf16 hi/lo split, 3-term Ootomo precision).
// d(x,y) = |y|^2 - 2x.y + |x|^2 packed as a K=13 dot product in
// mfma_f32_32x32x16_bf16 (lanes<32 carry k=0..7 slots, lanes>=32 k=8..15).
// Min over y: in-lane reduce of the 16 accumulator regs + shfl_xor(32) fold.
// Math verbatim from rounds 4/7/8 (absmax 0.0 each time).
//
// Round-9: (1) explicit 2-deep MFMA pipeline with STATIC accumulator names
// (Da/Db, no runtime indexing, no inline asm -> compiler handles MFMA hazards
// and keeps both in flight); (2) min3-shaped fminf triples (clang fuses to
// v_min3_f32): 8 reduce ops per MFMA instead of 16; (3) YSEG 32 -> 2048
// blocks, 8 blocks/CU, for latency hiding. r5/6 lesson: no asm on MFMA results.

typedef float f32x16 __attribute__((ext_vector_type(16)));
typedef short bf16x8 __attribute__((ext_vector_type(8)));

constexpr int NPTS    = 8192;
constexpr int BATCH   = 4;
constexpr int NPT_TOT = 2 * BATCH * NPTS;   // 65536 rows total
constexpr int NRED    = 256;                // reduce blocks

__device__ __forceinline__ ushort bf16_rne(float v, float& back) {
    unsigned u = __float_as_uint(v);
    unsigned r = (u + 0x7FFFu + ((u >> 16) & 1u)) >> 16;
    back = __uint_as_float(r << 16);
    return (ushort)r;
}

union FragU { ushort u[8]; uint4 q; bf16x8 v; };

// 16 MFMA outputs + running min, shaped as triples so clang emits v_min3_f32
#define RED16(D, m) do {                                          \
    float a0 = fminf(fminf((D)[0],  (D)[1]),  (D)[2]);            \
    float a1 = fminf(fminf((D)[3],  (D)[4]),  (D)[5]);            \
    float a2 = fminf(fminf((D)[6],  (D)[7]),  (D)[8]);            \
    float a3 = fminf(fminf((D)[9],  (D)[10]), (D)[11]);           \
    float a4 = fminf(fminf((D)[12], (D)[13]), (D)[14]);           \
    float b0 = fminf(fminf(a0, a1), (D)[15]);                     \
    float b1 = fminf(fminf(a2, a3), a4);                          \
    (m) = fminf(fminf((m), b0), b1);                              \
} while (0)

template<int YSEG>
__global__ __launch_bounds__(256)
void chamfer_fused(const float* __restrict__ P1, const float* __restrict__ P2,
                   float* __restrict__ mintab) {
    constexpr int SEG = NPTS / YSEG;
    const int tid  = threadIdx.x;
    const int lane = tid & 63;
    const int w    = tid >> 6;
    const int col  = lane & 31;
    const int g    = lane >> 5;          // k-half: 0 -> slots 0-7, 1 -> slots 8-15

    const int xblk = blockIdx.x;         // 0..7   (1024 x-points per block)
    const int comb = blockIdx.y;         // 0..7   dir*4+b
    const int yseg = blockIdx.z;         // 0..YSEG-1
    const int dir  = comb >> 2;
    const int b    = comb & 3;

    const float* Xb = (dir ? P2 : P1) + (size_t)b * NPTS * 3;
    const float* Yb = (dir ? P1 : P2) + (size_t)b * NPTS * 3 + (size_t)yseg * SEG * 3;

    __shared__ uint4 lds_a[2 * SEG];     // [half][yp] A-role fragments

    // ---- build A-role frags for this block's SEG y-points ----
    for (int yp = tid; yp < SEG; yp += 256) {
        const float v0 = Yb[yp * 3 + 0], v1 = Yb[yp * 3 + 1], v2 = Yb[yp * 3 + 2];
        float h0f, h1f, h2f, d;
        const ushort h0 = bf16_rne(v0, h0f);
        const ushort h1 = bf16_rne(v1, h1f);
        const ushort h2 = bf16_rne(v2, h2f);
        const ushort l0 = bf16_rne(v0 - h0f, d);
        const ushort l1 = bf16_rne(v1 - h1f, d);
        const ushort l2 = bf16_rne(v2 - h2f, d);
        const float  s  = fmaf(v0, v0, fmaf(v1, v1, v2 * v2));
        float shf;
        const ushort sh = bf16_rne(s, shf);
        const ushort sl = bf16_rne(s - shf, d);
        const ushort ONE = 0x3F80;
        FragU A0, A1;
        A0.u[0]=h0; A0.u[1]=h1; A0.u[2]=h2; A0.u[3]=l0; A0.u[4]=l1; A0.u[5]=l2; A0.u[6]=h0; A0.u[7]=h1;
        A1.u[0]=h2; A1.u[1]=sh; A1.u[2]=sl; A1.u[3]=ONE; A1.u[4]=ONE; A1.u[5]=0; A1.u[6]=0; A1.u[7]=0;
        lds_a[yp]       = A0.q;
        lds_a[SEG + yp] = A1.q;
    }

    // ---- build B-role frags in registers (this wave's 256 x-points) ----
    const int xloc = xblk * 1024 + w * 256;
    bf16x8 Bf[8];
    #pragma unroll
    for (int t = 0; t < 8; ++t) {
        const int xp = xloc + t * 32 + col;
        const float v0 = Xb[xp * 3 + 0], v1 = Xb[xp * 3 + 1], v2 = Xb[xp * 3 + 2];
        float h0f, h1f, h2f, dd;
        bf16_rne(v0, h0f); bf16_rne(v1, h1f); bf16_rne(v2, h2f);
        float l0f, l1f, l2f;
        bf16_rne(v0 - h0f, l0f); bf16_rne(v1 - h1f, l1f); bf16_rne(v2 - h2f, l2f);
        const ushort n0 = bf16_rne(-2.f * h0f, dd);
        const ushort n1 = bf16_rne(-2.f * h1f, dd);
        const ushort n2 = bf16_rne(-2.f * h2f, dd);
        const ushort m0 = bf16_rne(-2.f * l0f, dd);
        const ushort m1 = bf16_rne(-2.f * l1f, dd);
        const ushort m2 = bf16_rne(-2.f * l2f, dd);
        const float  s  = fmaf(v0, v0, fmaf(v1, v1, v2 * v2));
        float shf;
        const ushort sh = bf16_rne(s, shf);
        const ushort sl = bf16_rne(s - shf, dd);
        const ushort ONE = 0x3F80;
        FragU B;
        B.u[0] = g ? m2  : n0;
        B.u[1] = g ? ONE : n1;
        B.u[2] = g ? ONE : n2;
        B.u[3] = g ? sh  : n0;
        B.u[4] = g ? sl  : n1;
        B.u[5] = g ? 0   : n2;
        B.u[6] = g ? 0   : m0;
        B.u[7] = g ? 0   : m1;
        Bf[t] = B.v;
    }
    __syncthreads();

    // ---- main loop: 2-deep static pipeline, reduce(t) overlaps mfma(t+1) ----
    const f32x16 zero = {};
    float md[8];
    #pragma unroll
    for (int t = 0; t < 8; ++t) md[t] = 1e30f;

    #pragma unroll
    for (int yi = 0; yi < SEG / 32; ++yi) {
        FragU AfU;
        AfU.q = lds_a[g * SEG + yi * 32 + col];
        const bf16x8 Af = AfU.v;
        f32x16 Da = __builtin_amdgcn_mfma_f32_32x32x16_bf16(Af, Bf[0], zero, 0, 0, 0);
        f32x16 Db = __builtin_amdgcn_mfma_f32_32x32x16_bf16(Af, Bf[1], zero, 0, 0, 0);
        RED16(Da, md[0]);
        Da = __builtin_amdgcn_mfma_f32_32x32x16_bf16(Af, Bf[2], zero, 0, 0, 0);
        RED16(Db, md[1]);
        Db = __builtin_amdgcn_mfma_f32_32x32x16_bf16(Af, Bf[3], zero, 0, 0, 0);
        RED16(Da, md[2]);
        Da = __builtin_amdgcn_mfma_f32_32x32x16_bf16(Af, Bf[4], zero, 0, 0, 0);
        RED16(Db, md[3]);
        Db = __builtin_amdgcn_mfma_f32_32x32x16_bf16(Af, Bf[5], zero, 0, 0, 0);
        RED16(Da, md[4]);
        Da = __builtin_amdgcn_mfma_f32_32x32x16_bf16(Af, Bf[6], zero, 0, 0, 0);
        RED16(Db, md[5]);
        Db = __builtin_amdgcn_mfma_f32_32x32x16_bf16(Af, Bf[7], zero, 0, 0, 0);
        RED16(Da, md[6]);
        RED16(Db, md[7]);
    }

    #pragma unroll
    for (int t = 0; t < 8; ++t)
        md[t] = fminf(md[t], __shfl_xor(md[t], 32, 64));

    if (g == 0) {
        const size_t rowbase = (size_t)yseg * NPT_TOT
                             + (size_t)(dir * BATCH + b) * NPTS + xloc;
        #pragma unroll
        for (int t = 0; t < 8; ++t)
            mintab[rowbase + t * 32 + col] = md[t];
    }
}

template<int YSEG>
__global__ __launch_bounds__(256)
void chamfer_reduce(const float* __restrict__ mintab, float* __restrict__ partials) {
    const int r = blockIdx.x * 256 + threadIdx.x;
    float m = mintab[r];
    #pragma unroll
    for (int s = 1; s < YSEG; ++s)
        m = fminf(m, mintab[(size_t)s * NPT_TOT + r]);
    float v = sqrtf(fmaxf(m, 0.f));
    #pragma unroll
    for (int off = 32; off; off >>= 1) v += __shfl_down(v, off, 64);
    __shared__ float ws[4];
    const int tid = threadIdx.x;
    if ((tid & 63) == 0) ws[tid >> 6] = v;
    __syncthreads();
    if (tid == 0)
        partials[blockIdx.x] = ws[0] + ws[1] + ws[2] + ws[3];   // plain store, no init
}

__global__ __launch_bounds__(256)
void chamfer_final(const float* __restrict__ partials, float* __restrict__ out) {
    const int tid = threadIdx.x;
    float v = partials[tid];                 // NRED == 256 == blockDim
    #pragma unroll
    for (int off = 32; off; off >>= 1) v += __shfl_down(v, off, 64);
    __shared__ float ws[4];
    if ((tid & 63) == 0) ws[tid >> 6] = v;
    __syncthreads();
    if (tid == 0)
        out[0] = (ws[0] + ws[1] + ws[2] + ws[3]) * (1.0f / NPT_TOT);
}

extern "C" void kernel_launch(void* const* d_in, const int* in_sizes, int n_in,
                              void* d_out, int out_size, void* d_ws, size_t ws_size,
                              hipStream_t stream) {
    const float* p1 = (const float*)d_in[0];
    const float* p2 = (const float*)d_in[1];
    float* out = (float*)d_out;

    const size_t need32 = (size_t)32 * NPT_TOT * 4 + NRED * 4;   // 8 MB + 1 KB
    if (ws_size >= need32) {
        constexpr int YSEG = 32;
        float* mintab   = (float*)d_ws;
        float* partials = (float*)((char*)d_ws + (size_t)YSEG * NPT_TOT * 4);
        chamfer_fused<YSEG><<<dim3(8, 8, YSEG), 256, 0, stream>>>(p1, p2, mintab);
        chamfer_reduce<YSEG><<<dim3(NRED), 256, 0, stream>>>(mintab, partials);
        chamfer_final<<<1, 256, 0, stream>>>(partials, out);
    } else {
        constexpr int YSEG = 16;
        float* mintab   = (float*)d_ws;
        float* partials = (float*)((char*)d_ws + (size_t)YSEG * NPT_TOT * 4);
        chamfer_fused<YSEG><<<dim3(8, 8, YSEG), 256, 0, stream>>>(p1, p2, mintab);
        chamfer_reduce<YSEG><<<dim3(NRED), 256, 0, stream>>>(mintab, partials);
        chamfer_final<<<1, 256, 0, stream>>>(partials, out);
    }
}